// Round 2
// baseline (1049.897 us; speedup 1.0000x reference)
//
#include <hip/hip_runtime.h>

// IF-neuron, exact-match strategy: compute x = inp @ W^T + bias and the scan
// entirely in fp64 (vector v_fma_f64 — NO MFMA, no fragment-layout assumptions).
// f32*f32 products are exact in f64; only fp64 accumulation rounding (~1e-13)
// separates us from a numpy-fp64 reference, so spike decisions match.
//
// Structure: chunked over T by ws_size:
//   dgemm_f64  : x[tl*B+b][o] (f64, in d_ws) for a chunk of T
//   if_scan    : carries (mem, spike, cnt) state per (b,o) across chunks
// Emergency path (ws < ~5 MB): fused naive kernel, no workspace.

#define T_ALL 32
#define B_DIM 128
#define O_DIM 2048
#define K_DIM 2048
#define BO    (B_DIM * O_DIM)   // 262144 outputs

#define BM 128
#define BN 64
#define BK 16

// C[m][n] = sum_k A[m_off + m][k] * W[n][k]   (A: [4096][2048] f32 = inp viewed [T*B][K])
__global__ __launch_bounds__(256) void dgemm_f64(
    const float* __restrict__ Ag, const float* __restrict__ Wg,
    double* __restrict__ Cx, int m_off)
{
    __shared__ double As[BM][BK + 1];
    __shared__ double Ws[BN][BK + 1];

    const int tid = threadIdx.x;
    const int n0 = blockIdx.x * BN;
    const int m0 = blockIdx.y * BM;
    const int tm = tid >> 4;   // 0..15 -> rows tm*8 .. tm*8+7
    const int to = tid & 15;   // 0..15 -> cols to*4 .. to*4+3

    double acc[8][4];
#pragma unroll
    for (int i = 0; i < 8; ++i)
#pragma unroll
        for (int j = 0; j < 4; ++j) acc[i][j] = 0.0;

    const float* Arow = Ag + (size_t)(m_off + m0) * K_DIM;
    const float* Wrow = Wg + (size_t)n0 * K_DIM;

    for (int k0 = 0; k0 < K_DIM; k0 += BK) {
#pragma unroll
        for (int p = 0; p < 2; ++p) {                 // stage A tile: 128 x 16
            int idx = p * 256 + tid;                   // 0..511
            int r = idx >> 2, c4 = idx & 3;
            float4 v = *reinterpret_cast<const float4*>(Arow + (size_t)r * K_DIM + k0 + c4 * 4);
            As[r][c4 * 4 + 0] = (double)v.x; As[r][c4 * 4 + 1] = (double)v.y;
            As[r][c4 * 4 + 2] = (double)v.z; As[r][c4 * 4 + 3] = (double)v.w;
        }
        {                                              // stage W tile: 64 x 16
            int r = tid >> 2, c4 = tid & 3;
            float4 v = *reinterpret_cast<const float4*>(Wrow + (size_t)r * K_DIM + k0 + c4 * 4);
            Ws[r][c4 * 4 + 0] = (double)v.x; Ws[r][c4 * 4 + 1] = (double)v.y;
            Ws[r][c4 * 4 + 2] = (double)v.z; Ws[r][c4 * 4 + 3] = (double)v.w;
        }
        __syncthreads();
#pragma unroll
        for (int kk = 0; kk < BK; ++kk) {
            double a[8], w[4];
#pragma unroll
            for (int i = 0; i < 8; ++i) a[i] = As[tm * 8 + i][kk];
#pragma unroll
            for (int j = 0; j < 4; ++j) w[j] = Ws[to * 4 + j][kk];
#pragma unroll
            for (int i = 0; i < 8; ++i)
#pragma unroll
                for (int j = 0; j < 4; ++j) acc[i][j] = fma(a[i], w[j], acc[i][j]);
        }
        __syncthreads();
    }
#pragma unroll
    for (int i = 0; i < 8; ++i)
#pragma unroll
        for (int j = 0; j < 4; ++j)
            Cx[(size_t)(m0 + tm * 8 + i) * O_DIM + n0 + to * 4 + j] = acc[i][j];
}

// scan over a chunk of t; state packed: cnt | (sp<<16)
__global__ __launch_bounds__(256) void if_scan(
    const double* __restrict__ xbuf, const float* __restrict__ bias,
    const float* __restrict__ mem0,
    double* __restrict__ mem_st, int* __restrict__ cnt_st,
    float* __restrict__ outp, int t_begin, int t_count)
{
    const int i = blockIdx.x * 256 + threadIdx.x;   // (b,o) flat
    const int o = i & (O_DIM - 1);

    double mem; int cnt; bool sp;
    if (t_begin == 0) { mem = (double)mem0[i]; cnt = 0; sp = false; }
    else { mem = mem_st[i]; int c = cnt_st[i]; cnt = c & 0xffff; sp = (c >> 16) & 1; }

    const double biasd = (double)bias[o];
    for (int tl = 0; tl < t_count; ++tl) {
        double xv = xbuf[(size_t)tl * BO + i] + biasd;
        mem = (sp ? 0.0 : mem) + xv;    // reset-by-mask + integrate
        sp = (mem > 1.0);               // fire (strict >)
        cnt += sp ? 1 : 0;
    }
    if (t_begin + t_count >= T_ALL) outp[i] = (float)cnt * 0.03125f;
    else { mem_st[i] = mem; cnt_st[i] = cnt | (sp ? (1 << 16) : 0); }
}

// emergency: no workspace. One thread per (b,o); inp row staged in LDS.
__global__ __launch_bounds__(256) void if_fused_naive(
    const float* __restrict__ inp, const float* __restrict__ Wm,
    const float* __restrict__ bias, const float* __restrict__ mem0,
    float* __restrict__ outp)
{
    __shared__ float xr[K_DIM];
    const int i = blockIdx.x * 256 + threadIdx.x;
    const int b = i >> 11, o = i & (O_DIM - 1);   // b constant within block
    double mem = (double)mem0[i];
    const double biasd = (double)bias[o];
    int cnt = 0; bool sp = false;
    const float* wrow = Wm + (size_t)o * K_DIM;
    for (int t = 0; t < T_ALL; ++t) {
        for (int k = threadIdx.x; k < K_DIM; k += 256)
            xr[k] = inp[((size_t)t * B_DIM + b) * K_DIM + k];
        __syncthreads();
        double d0 = 0.0, d1 = 0.0;
        for (int k = 0; k < K_DIM; k += 2) {
            d0 = fma((double)xr[k],     (double)wrow[k],     d0);
            d1 = fma((double)xr[k + 1], (double)wrow[k + 1], d1);
        }
        double xv = (d0 + d1) + biasd;
        mem = (sp ? 0.0 : mem) + xv;
        sp = (mem > 1.0);
        cnt += sp ? 1 : 0;
        __syncthreads();
    }
    outp[i] = (float)cnt * 0.03125f;
}

extern "C" void kernel_launch(void* const* d_in, const int* in_sizes, int n_in,
                              void* d_out, int out_size, void* d_ws, size_t ws_size,
                              hipStream_t stream) {
    const float* inp  = (const float*)d_in[0];   // [32,128,2048]
    const float* Wm   = (const float*)d_in[1];   // [2048,2048]
    const float* bias = (const float*)d_in[2];   // [2048]
    const float* mem0 = (const float*)d_in[3];   // [128,2048]
    float* outp = (float*)d_out;                 // [128,2048]

    const size_t st_bytes = (size_t)BO * 8 + (size_t)BO * 4;   // mem_st + cnt_st = 3 MB

    if (ws_size < st_bytes + (size_t)BO * 8) {   // can't even fit one t-plane
        if_fused_naive<<<BO / 256, 256, 0, stream>>>(inp, Wm, bias, mem0, outp);
        return;
    }

    int tc = T_ALL;
    while (tc > 1 && st_bytes + (size_t)tc * BO * 8 > ws_size) tc >>= 1;

    double* mem_st = (double*)d_ws;
    int*    cnt_st = (int*)((char*)d_ws + (size_t)BO * 8);
    double* xbuf   = (double*)((char*)d_ws + st_bytes);

    for (int tb = 0; tb < T_ALL; tb += tc) {
        dim3 g(O_DIM / BN, (tc * B_DIM) / BM);
        dgemm_f64<<<g, 256, 0, stream>>>(inp, Wm, xbuf, tb * B_DIM);
        if_scan<<<BO / 256, 256, 0, stream>>>(xbuf, bias, mem0, mem_st, cnt_st,
                                              outp, tb, tc);
    }
}